// Round 5
// baseline (303.279 us; speedup 1.0000x reference)
//
#include <hip/hip_runtime.h>
#include <cstdint>

using u16 = unsigned short;
using u32 = unsigned int;

constexpr int kB  = 4096;
constexpr int kE  = 512;
constexpr int kT  = 32;
constexpr int kH  = 256;
constexpr int kIT = 5;
constexpr float kEPS = 1e-6f;

typedef __attribute__((ext_vector_type(8)))  short short8;
typedef __attribute__((ext_vector_type(16))) float floatx16;
typedef __attribute__((ext_vector_type(8)))  u16   ushort8;
typedef __attribute__((ext_vector_type(4)))  float floatv4;  // native vec for nt builtins

__device__ __forceinline__ u16 f2bf(float f) {
  u32 u = __builtin_bit_cast(u32, f);
  return (u16)((u + 0x7fffu + ((u >> 16) & 1u)) >> 16);
}

__device__ __forceinline__ floatx16 mfma32(short8 a, short8 b, floatx16 c) {
  return __builtin_amdgcn_mfma_f32_32x32x16_bf16(a, b, c, 0, 0, 0);
}

__device__ __forceinline__ void ntstore4(float* p, float4 v) {
  __builtin_nontemporal_store(__builtin_bit_cast(floatv4, v), (floatv4*)p);
}

// async global->LDS, 16B per lane; LDS dest = wave-uniform base + lane*16 (HW rule),
// global src = per-lane address. Our packed chunks are exactly 64 lanes x 16B.
__device__ __forceinline__ void gload16(const u16* gsrc, u16* ldst) {
  __builtin_amdgcn_global_load_lds(
      (const __attribute__((address_space(1))) u32*)gsrc,
      (__attribute__((address_space(3))) u32*)ldst, 16, 0, 0);
}

// ---------------- pack_x (R6, verified): coalesced LDS transpose ----------------
// xp chunk c = slab*64 + ks*2 + mt ; lane l holds row=slab*64+mt*32+(l&31),
// k = ks*16+(l>>5)*8+j
__global__ __launch_bounds__(256) void pack_x_kernel(
    const float* __restrict__ x, u16* __restrict__ xp) {
  __shared__ __attribute__((aligned(16))) float tile[64 * 132];
  const int slab = blockIdx.x >> 2;
  const int kg   = blockIdx.x & 3;
  const int tid  = threadIdx.x;

  const int r0 = tid >> 5;          // 0..7
  const int c0 = (tid & 31) * 4;    // 0..124
#pragma unroll
  for (int p = 0; p < 8; ++p) {
    const int r = p * 8 + r0;
    const float4 v = *(const float4*)(x + (size_t)(slab * 64 + r) * kE + kg * 128 + c0);
    *(float4*)(tile + r * 132 + c0) = v;
  }
  __syncthreads();

  const int wv = tid >> 6, lane = tid & 63;
#pragma unroll
  for (int q = 0; q < 4; ++q) {
    const int cc   = wv * 4 + q;       // 0..15
    const int ks_l = cc >> 1;          // 0..7
    const int mt   = cc & 1;
    const int rl   = mt * 32 + (lane & 31);
    const int kl   = ks_l * 16 + (lane >> 5) * 8;
    const float4 f0 = *(const float4*)(tile + rl * 132 + kl);
    const float4 f1 = *(const float4*)(tile + rl * 132 + kl + 4);
    ushort8 o;
    o[0] = f2bf(f0.x); o[1] = f2bf(f0.y); o[2] = f2bf(f0.z); o[3] = f2bf(f0.w);
    o[4] = f2bf(f1.x); o[5] = f2bf(f1.y); o[6] = f2bf(f1.z); o[7] = f2bf(f1.w);
    const int c = slab * 64 + (kg * 8 + ks_l) * 2 + mt;
    *(ushort8*)(xp + (size_t)c * 512 + lane * 8) = o;
  }
}

// ---------------- pack_w (R6, verified): LDS transpose, cached loads ----------
// wp chunk c = t*512 + ks*16 + ntile*2 + mat : lane l holds n=ntile*32+(l&31),
// k=ks*16+(l>>5)*8+j
__global__ __launch_bounds__(256) void pack_w_kernel(
    const float* __restrict__ w_in, const float* __restrict__ w_val,
    u16* __restrict__ wp) {
  __shared__ __attribute__((aligned(16))) float tile[64 * 68];
  const int wb   = blockIdx.x;
  const int tl   = wb & 31;
  const int et   = tl >> 2;
  const int ht   = tl & 3;
  const int tm   = wb >> 5;
  const int t    = tm >> 1, mat = tm & 1;
  const int tid  = threadIdx.x;
  const float* src = (mat ? w_val : w_in) + (size_t)t * kE * kH +
                     (size_t)(et * 64) * kH + ht * 64;
  const int lrow = tid >> 4, lc4 = (tid & 15) * 4;
#pragma unroll
  for (int p = 0; p < 4; ++p) {
    const int e = lrow + p * 16;
    const float4 v = *(const float4*)(src + (size_t)e * kH + lc4);
    tile[e * 68 + lc4 + 0] = v.x; tile[e * 68 + lc4 + 1] = v.y;
    tile[e * 68 + lc4 + 2] = v.z; tile[e * 68 + lc4 + 3] = v.w;
  }
  __syncthreads();
  const int ks_l = tid >> 6, lane = tid & 63;
  const int kloc = ks_l * 16 + (lane >> 5) * 8;
#pragma unroll
  for (int nt_l = 0; nt_l < 2; ++nt_l) {
    const int nloc = nt_l * 32 + (lane & 31);
    ushort8 o;
#pragma unroll
    for (int j = 0; j < 8; ++j) o[j] = f2bf(tile[(kloc + j) * 68 + nloc]);
    const int c = t * 512 + (et * 4 + ks_l) * 16 + (ht * 2 + nt_l) * 2 + mat;
    *(ushort8*)(wp + (size_t)c * 512 + lane * 8) = o;
  }
}

// ---------------- fused R9: R8 skeleton, manual fences REMOVED ----------------
// A/B vs R8: identical data paths, ring, mapping, epilogue. Changes only:
//  * dropped per-phase `s_waitcnt lgkmcnt(0)` + sched_barrier before MFMAs
//    (m141/common-mistake-#5: manual drains defeat the compiler's counted
//    lgkmcnt pipelining; ds_reads here are compiler-visible C++ loads, so the
//    scoreboard waits are auto-inserted and FINE-GRAINED: MFMAs start after 3
//    of 6 reads instead of all 6).
//  * dropped setprio (m190: hurts GEMM-shaped loops).
//  * ONE sched_barrier(0) per phase (after the vmcnt wall, before issue):
//    pins program order so batch p+3's gload (writer of slot p%3) cannot be
//    hoisted above phase-p MFMAs. Since every staged chunk of phase p feeds a
//    phase-p MFMA, all 6 ds_reads COMPLETE before those MFMAs issue -> reads
//    of slot s are complete before its next writer is even issued: structural
//    slot-reuse safety without any lgkm drain.
// Sync remains per-wave counted vmcnt: batch p issued at phase p-2.
__global__ __launch_bounds__(256, 2) void fused_kernel(
    const u16* __restrict__ xp, const u16* __restrict__ wp,
    const float* __restrict__ alphas, const float* __restrict__ scales,
    const float* __restrict__ gamma, const float* __restrict__ beta,
    float* __restrict__ out) {
  __shared__ __attribute__((aligned(16))) u16 ring[4][3][3072];  // 72KB
  float* sAcc = (float*)ring;  // 32KB epilogue scratch, aliases the ring

  const int tid  = threadIdx.x;
  const int wv   = tid >> 6;
  const int lane = tid & 63;
  const int l31  = lane & 31;
  const int h    = lane >> 5;

  const int bid  = blockIdx.x;
  const int xcd  = bid & 7;
  const int r_   = bid >> 3;
  const int st   = r_ >> 6;
  const int wi   = r_ & 63;
  const int t    = xcd * 4 + (wi >> 4);
  const int slab = st * 16 + (wi & 15);

  // per-wave global source bases (chunk = 512 u16 = 1KB = 64 lanes x 16B)
  const u16* xsrc = xp + (size_t)slab * (32 * 2 * 512) + lane * 8;          // A: chunk p*2+{0,1}
  const u16* bsrc = wp + (size_t)t * (32 * 16 * 512) + (wv * 4) * 512 + lane * 8;  // B: chunk p*16+wv*4+{0..3}
  u16* const ring_w = &ring[wv][0][0];

  floatx16 ai[2][2], av[2][2];
#pragma unroll
  for (int m = 0; m < 2; ++m)
#pragma unroll
    for (int n = 0; n < 2; ++n) { ai[m][n] = (floatx16)0.f; av[m][n] = (floatx16)0.f; }

  auto issue = [&](int pb, int slot) {
    u16* d = ring_w + slot * 3072;
    const u16* a = xsrc + (size_t)pb * 1024;
    const u16* b = bsrc + (size_t)pb * 8192;
    gload16(a,        d);
    gload16(a + 512,  d + 512);
    gload16(b,        d + 1024);
    gload16(b + 512,  d + 1536);
    gload16(b + 1024, d + 2048);
    gload16(b + 1536, d + 2560);
  };

  // prologue: batches 0,1 in flight (12 outstanding)
  issue(0, 0);
  issue(1, 1);

#pragma unroll
  for (int p = 0; p < 32; ++p) {
    // wall: batch p landed (issued at p-2; two compute phases of cover)
    if (p < 31) { asm volatile("s_waitcnt vmcnt(6)" ::: "memory"); }
    else        { asm volatile("s_waitcnt vmcnt(0)" ::: "memory"); }
    __builtin_amdgcn_sched_barrier(0);  // pin phase boundary (slot-reuse safety)
    if (p < 30) issue(p + 2, (p + 2) % 3);

    const u16* base = ring_w + (p % 3) * 3072 + lane * 8;
    const short8 A0  = *(const short8*)(base);
    const short8 A1  = *(const short8*)(base + 512);
    const short8 BI0 = *(const short8*)(base + 1024);
    const short8 BV0 = *(const short8*)(base + 1536);
    const short8 BI1 = *(const short8*)(base + 2048);
    const short8 BV1 = *(const short8*)(base + 2560);
    // NO manual lgkm fence: compiler emits counted lgkmcnt between ds_read
    // and each dependent MFMA (near-optimal per m97 asm evidence).
    ai[0][0] = mfma32(A0, BI0, ai[0][0]);
    ai[1][0] = mfma32(A1, BI0, ai[1][0]);
    ai[0][1] = mfma32(A0, BI1, ai[0][1]);
    ai[1][1] = mfma32(A1, BI1, ai[1][1]);
    av[0][0] = mfma32(A0, BV0, av[0][0]);
    av[1][0] = mfma32(A1, BV0, av[1][0]);
    av[0][1] = mfma32(A0, BV1, av[0][1]);
    av[1][1] = mfma32(A1, BV1, av[1][1]);
  }

  // ---- epilogue (verified in R4; nt final stores) ----
  const float inv_h = 1.0f / kH;
  float al[kIT];
#pragma unroll
  for (int i = 0; i < kIT; ++i) al[i] = alphas[t * kIT + i] * inv_h;

  const int row_r = tid >> 3;
  const int seg   = tid & 7;
  const int r4    = (row_r & 7) << 2;

#pragma unroll
  for (int mt = 0; mt < 2; ++mt) {
    __syncthreads();
#pragma unroll
    for (int nt = 0; nt < 2; ++nt)
#pragma unroll
      for (int q = 0; q < 16; ++q) {
        const int r   = (q & 3) + 8 * (q >> 2) + 4 * h;
        const int col = wv * 64 + nt * 32 + l31;
        sAcc[r * 256 + (col ^ ((r & 7) << 2))] = ai[mt][nt][q];
      }
    __syncthreads();

    float4 xt[8];
#pragma unroll
    for (int j = 0; j < 8; ++j) {
      xt[j] = *(const float4*)(sAcc + row_r * 256 + seg * 32 + ((4 * j) ^ r4));
#pragma unroll
      for (int i = 0; i < 4; ++i) xt[j][i] = fmaxf(xt[j][i], 0.f);
    }

#pragma unroll
    for (int it = 0; it < kIT; ++it) {
      float4 s4 = xt[0];
#pragma unroll
      for (int j = 1; j < 8; ++j) s4 += xt[j];
      float v = s4.x + s4.y + s4.z + s4.w;
      v += __shfl_xor(v, 1, 8);
      v += __shfl_xor(v, 2, 8);
      v += __shfl_xor(v, 4, 8);
      const float m = al[it] * v;
#pragma unroll
      for (int j = 0; j < 8; ++j)
#pragma unroll
        for (int i = 0; i < 4; ++i) xt[j][i] = fmaxf(xt[j][i] - m, 0.f);
    }

    __syncthreads();
#pragma unroll
    for (int nt = 0; nt < 2; ++nt)
#pragma unroll
      for (int q = 0; q < 16; ++q) {
        const int r   = (q & 3) + 8 * (q >> 2) + 4 * h;
        const int col = wv * 64 + nt * 32 + l31;
        sAcc[r * 256 + (col ^ ((r & 7) << 2))] = av[mt][nt][q];
      }
    __syncthreads();

    float4 res[8];
    float sum = 0.f, ssq = 0.f;
#pragma unroll
    for (int j = 0; j < 8; ++j) {
      const int cb = seg * 32 + ((4 * j) ^ r4);  // physical LDS offset
      const int lc = seg * 32 + 4 * j;           // logical column
      const float4 a4 = *(const float4*)(sAcc + row_r * 256 + cb);
      const float4 sc = *(const float4*)(scales + t * kH + lc);
      float4 s;
#pragma unroll
      for (int i = 0; i < 4; ++i) {
        s[i] = sc[i] * xt[j][i] * a4[i];
        sum += s[i];
        ssq += s[i] * s[i];
      }
      res[j] = s;
    }
    sum += __shfl_xor(sum, 1, 8);  ssq += __shfl_xor(ssq, 1, 8);
    sum += __shfl_xor(sum, 2, 8);  ssq += __shfl_xor(ssq, 2, 8);
    sum += __shfl_xor(sum, 4, 8);  ssq += __shfl_xor(ssq, 4, 8);
    const float mu  = sum * inv_h;
    const float var = ssq * inv_h - mu * mu;
    const float rs  = rsqrtf(var + kEPS);

#pragma unroll
    for (int j = 0; j < 8; ++j) {
      const int cb = seg * 32 + ((4 * j) ^ r4);
      const int lc = seg * 32 + 4 * j;
      const float4 g4 = *(const float4*)(gamma + t * kH + lc);
      const float4 b4 = *(const float4*)(beta + t * kH + lc);
      float4 o;
#pragma unroll
      for (int i = 0; i < 4; ++i) o[i] = (res[j][i] - mu) * rs * g4[i] + b4[i];
      *(float4*)(sAcc + row_r * 256 + cb) = o;
    }
    __syncthreads();

    // coalesced non-temporal sweep: keep output stream out of L2
#pragma unroll
    for (int r8 = 0; r8 < 8; ++r8) {
      const int rr = wv * 8 + r8;
      const int rb = (rr & 7) << 2;
      const float4 v = *(const float4*)(sAcc + rr * 256 + ((4 * lane) ^ rb));
      ntstore4(out + (size_t)(slab * 64 + mt * 32 + rr) * (kT * kH) + t * kH + 4 * lane, v);
    }
  }
}

extern "C" void kernel_launch(void* const* d_in, const int* in_sizes, int n_in,
                              void* d_out, int out_size, void* d_ws, size_t ws_size,
                              hipStream_t stream) {
  const float* x      = (const float*)d_in[0];
  const float* w_in   = (const float*)d_in[1];
  const float* w_val  = (const float*)d_in[2];
  const float* alphas = (const float*)d_in[3];
  const float* scales = (const float*)d_in[4];
  const float* gamma  = (const float*)d_in[5];
  const float* beta   = (const float*)d_in[6];
  float* out = (float*)d_out;

  // ws: xp 4MB (64*32*2 chunks * 1KB) | wp 16MB (32*32*16 chunks * 1KB)
  u16* xp = (u16*)d_ws;
  u16* wp = xp + (size_t)64 * 32 * 2 * 512;

  pack_x_kernel<<<256, 256, 0, stream>>>(x, xp);
  pack_w_kernel<<<2048, 256, 0, stream>>>(w_in, w_val, wp);
  fused_kernel<<<kT * (kB / 64), 256, 0, stream>>>(xp, wp, alphas, scales,
                                                   gamma, beta, out);
}

// Round 6
// 290.203 us; speedup vs baseline: 1.0451x; 1.0451x over previous
//
#include <hip/hip_runtime.h>
#include <cstdint>

using u16 = unsigned short;
using u32 = unsigned int;

constexpr int kB  = 4096;
constexpr int kE  = 512;
constexpr int kT  = 32;
constexpr int kH  = 256;
constexpr int kIT = 5;
constexpr float kEPS = 1e-6f;

typedef __attribute__((ext_vector_type(8)))  short short8;
typedef __attribute__((ext_vector_type(16))) float floatx16;
typedef __attribute__((ext_vector_type(8)))  u16   ushort8;
typedef __attribute__((ext_vector_type(4)))  float floatv4;  // native vec for nt builtins

__device__ __forceinline__ u16 f2bf(float f) {
  u32 u = __builtin_bit_cast(u32, f);
  return (u16)((u + 0x7fffu + ((u >> 16) & 1u)) >> 16);
}

__device__ __forceinline__ floatx16 mfma32(short8 a, short8 b, floatx16 c) {
  return __builtin_amdgcn_mfma_f32_32x32x16_bf16(a, b, c, 0, 0, 0);
}

__device__ __forceinline__ void ntstore4(float* p, float4 v) {
  __builtin_nontemporal_store(__builtin_bit_cast(floatv4, v), (floatv4*)p);
}

// ---------------- pack_x (R6, verified): coalesced LDS transpose ----------------
// xp chunk c = slab*64 + ks*2 + mt ; lane l holds row=slab*64+mt*32+(l&31),
// k = ks*16+(l>>5)*8+j
__global__ __launch_bounds__(256) void pack_x_kernel(
    const float* __restrict__ x, u16* __restrict__ xp) {
  __shared__ __attribute__((aligned(16))) float tile[64 * 132];
  const int slab = blockIdx.x >> 2;
  const int kg   = blockIdx.x & 3;
  const int tid  = threadIdx.x;

  const int r0 = tid >> 5;          // 0..7
  const int c0 = (tid & 31) * 4;    // 0..124
#pragma unroll
  for (int p = 0; p < 8; ++p) {
    const int r = p * 8 + r0;
    const float4 v = *(const float4*)(x + (size_t)(slab * 64 + r) * kE + kg * 128 + c0);
    *(float4*)(tile + r * 132 + c0) = v;
  }
  __syncthreads();

  const int wv = tid >> 6, lane = tid & 63;
#pragma unroll
  for (int q = 0; q < 4; ++q) {
    const int cc   = wv * 4 + q;       // 0..15
    const int ks_l = cc >> 1;          // 0..7
    const int mt   = cc & 1;
    const int rl   = mt * 32 + (lane & 31);
    const int kl   = ks_l * 16 + (lane >> 5) * 8;
    const float4 f0 = *(const float4*)(tile + rl * 132 + kl);
    const float4 f1 = *(const float4*)(tile + rl * 132 + kl + 4);
    ushort8 o;
    o[0] = f2bf(f0.x); o[1] = f2bf(f0.y); o[2] = f2bf(f0.z); o[3] = f2bf(f0.w);
    o[4] = f2bf(f1.x); o[5] = f2bf(f1.y); o[6] = f2bf(f1.z); o[7] = f2bf(f1.w);
    const int c = slab * 64 + (kg * 8 + ks_l) * 2 + mt;
    *(ushort8*)(xp + (size_t)c * 512 + lane * 8) = o;
  }
}

// ---------------- pack_w (R6, verified): LDS transpose, cached loads ----------
// wp chunk c = t*512 + ks*16 + ntile*2 + mat : lane l holds n=ntile*32+(l&31),
// k=ks*16+(l>>5)*8+j
__global__ __launch_bounds__(256) void pack_w_kernel(
    const float* __restrict__ w_in, const float* __restrict__ w_val,
    u16* __restrict__ wp) {
  __shared__ __attribute__((aligned(16))) float tile[64 * 68];
  const int wb   = blockIdx.x;
  const int tl   = wb & 31;
  const int et   = tl >> 2;
  const int ht   = tl & 3;
  const int tm   = wb >> 5;
  const int t    = tm >> 1, mat = tm & 1;
  const int tid  = threadIdx.x;
  const float* src = (mat ? w_val : w_in) + (size_t)t * kE * kH +
                     (size_t)(et * 64) * kH + ht * 64;
  const int lrow = tid >> 4, lc4 = (tid & 15) * 4;
#pragma unroll
  for (int p = 0; p < 4; ++p) {
    const int e = lrow + p * 16;
    const float4 v = *(const float4*)(src + (size_t)e * kH + lc4);
    tile[e * 68 + lc4 + 0] = v.x; tile[e * 68 + lc4 + 1] = v.y;
    tile[e * 68 + lc4 + 2] = v.z; tile[e * 68 + lc4 + 3] = v.w;
  }
  __syncthreads();
  const int ks_l = tid >> 6, lane = tid & 63;
  const int kloc = ks_l * 16 + (lane >> 5) * 8;
#pragma unroll
  for (int nt_l = 0; nt_l < 2; ++nt_l) {
    const int nloc = nt_l * 32 + (lane & 31);
    ushort8 o;
#pragma unroll
    for (int j = 0; j < 8; ++j) o[j] = f2bf(tile[(kloc + j) * 68 + nloc]);
    const int c = t * 512 + (et * 4 + ks_l) * 16 + (ht * 2 + nt_l) * 2 + mat;
    *(ushort8*)(wp + (size_t)c * 512 + lane * 8) = o;
  }
}

// ---------------- fused R10: occupancy-first, zero-LDS K-loop --------------------
// Post-R9 accounting: MFMA needs only ~27us; ~135us was stall with 2 waves/SIMD.
// The LDS ring had ZERO reuse (operands already in fragment layout) - it was pure
// latency-decoupling at the cost of occupancy. R10: 512-thread blocks, 8 waves,
// wave tile 64x32 (acc = 4 floatx16 = 64 regs), fragments loaded DIRECTLY
// global->VGPR (plain loads: compiler inserts counted vmcnt; A chunks get L1 reuse
// across the 8 waves). __launch_bounds__(512,4) -> 4 waves/SIMD = 16 waves/CU
// (~50% occ): reg budget 64 acc + 32 frag ring + ~30 addr ~= 126 <= 128 cap.
// Latency: batch p+2 issued >=1 phase ahead; phase-round at 4 waves/SIMD ~ 1000cy
// of cover >> L2 (~200cy). Block still covers 64 rows x 256 cols so the H=256
// epilogue reduction stays block-local. Supertile/XCD mapping unchanged.
__global__ __launch_bounds__(512, 4) void fused_kernel(
    const u16* __restrict__ xp, const u16* __restrict__ wp,
    const float* __restrict__ alphas, const float* __restrict__ scales,
    const float* __restrict__ gamma, const float* __restrict__ beta,
    float* __restrict__ out) {
  __shared__ __attribute__((aligned(16))) float sAcc[32 * 256];  // 32KB

  const int tid  = threadIdx.x;
  const int wv   = tid >> 6;         // 0..7
  const int lane = tid & 63;
  const int l31  = lane & 31;
  const int h    = lane >> 5;

  const int bid  = blockIdx.x;
  const int xcd  = bid & 7;
  const int r_   = bid >> 3;
  const int st   = r_ >> 6;
  const int wi   = r_ & 63;
  const int t    = xcd * 4 + (wi >> 4);
  const int slab = st * 16 + (wi & 15);

  // per-wave fragment sources (chunk = 512 u16 = 1KB = 64 lanes x 16B)
  // A: chunks p*2+{0,1}; B (this wave's 32-col slice): chunks p*16 + wv*2 + {0,1}
  const u16* xsrc = xp + (size_t)slab * (32 * 2 * 512) + lane * 8;
  const u16* bsrc = wp + (size_t)t * (32 * 16 * 512) + (size_t)(wv * 2) * 512 + lane * 8;

  floatx16 ai[2], av[2];
#pragma unroll
  for (int m = 0; m < 2; ++m) { ai[m] = (floatx16)0.f; av[m] = (floatx16)0.f; }

  // 2-slot register ring; slot p&1 holds batch p. Refill happens AFTER the MFMAs
  // consume the slot (WAR resolved at issue), giving ~1 full phase of prefetch.
  short8 A0[2], A1[2], BI[2], BV[2];
#pragma unroll
  for (int pb = 0; pb < 2; ++pb) {
    A0[pb] = *(const short8*)(xsrc + pb * 1024);
    A1[pb] = *(const short8*)(xsrc + pb * 1024 + 512);
    BI[pb] = *(const short8*)(bsrc + (size_t)pb * 8192);
    BV[pb] = *(const short8*)(bsrc + (size_t)pb * 8192 + 512);
  }

#pragma unroll
  for (int p = 0; p < 32; ++p) {
    const int cur = p & 1;
    ai[0] = mfma32(A0[cur], BI[cur], ai[0]);
    ai[1] = mfma32(A1[cur], BI[cur], ai[1]);
    av[0] = mfma32(A0[cur], BV[cur], av[0]);
    av[1] = mfma32(A1[cur], BV[cur], av[1]);
    if (p < 30) {
      A0[cur] = *(const short8*)(xsrc + (p + 2) * 1024);
      A1[cur] = *(const short8*)(xsrc + (p + 2) * 1024 + 512);
      BI[cur] = *(const short8*)(bsrc + (size_t)(p + 2) * 8192);
      BV[cur] = *(const short8*)(bsrc + (size_t)(p + 2) * 8192 + 512);
    }
  }

  // ---- epilogue: same verified algorithm, remapped for 512 threads ----
  // 16 threads per row (seg 0..15, 16 H each); shuffle groups of 16.
  const float inv_h = 1.0f / kH;
  float al[kIT];
#pragma unroll
  for (int i = 0; i < kIT; ++i) al[i] = alphas[t * kIT + i] * inv_h;

  const int row_r = tid >> 4;        // 0..31
  const int seg   = tid & 15;        // 0..15
  const int r4    = (row_r & 7) << 2;

#pragma unroll
  for (int mt = 0; mt < 2; ++mt) {
    __syncthreads();
#pragma unroll
    for (int q = 0; q < 16; ++q) {
      const int r   = (q & 3) + 8 * (q >> 2) + 4 * h;
      const int col = wv * 32 + l31;
      sAcc[r * 256 + (col ^ ((r & 7) << 2))] = ai[mt][q];
    }
    __syncthreads();

    float4 xt[4];
#pragma unroll
    for (int j = 0; j < 4; ++j) {
      xt[j] = *(const float4*)(sAcc + row_r * 256 + ((seg * 16 + 4 * j) ^ r4));
#pragma unroll
      for (int i = 0; i < 4; ++i) xt[j][i] = fmaxf(xt[j][i], 0.f);
    }

#pragma unroll
    for (int it = 0; it < kIT; ++it) {
      float4 s4 = xt[0];
#pragma unroll
      for (int j = 1; j < 4; ++j) s4 += xt[j];
      float v = s4.x + s4.y + s4.z + s4.w;
      v += __shfl_xor(v, 1, 16);
      v += __shfl_xor(v, 2, 16);
      v += __shfl_xor(v, 4, 16);
      v += __shfl_xor(v, 8, 16);
      const float m = al[it] * v;
#pragma unroll
      for (int j = 0; j < 4; ++j)
#pragma unroll
        for (int i = 0; i < 4; ++i) xt[j][i] = fmaxf(xt[j][i] - m, 0.f);
    }

    __syncthreads();
#pragma unroll
    for (int q = 0; q < 16; ++q) {
      const int r   = (q & 3) + 8 * (q >> 2) + 4 * h;
      const int col = wv * 32 + l31;
      sAcc[r * 256 + (col ^ ((r & 7) << 2))] = av[mt][q];
    }
    __syncthreads();

    float4 res[4];
    float sum = 0.f, ssq = 0.f;
#pragma unroll
    for (int j = 0; j < 4; ++j) {
      const int lc = seg * 16 + 4 * j;           // logical column
      const int cb = lc ^ r4;                    // physical LDS offset
      const float4 a4 = *(const float4*)(sAcc + row_r * 256 + cb);
      const float4 sc = *(const float4*)(scales + t * kH + lc);
      float4 s;
#pragma unroll
      for (int i = 0; i < 4; ++i) {
        s[i] = sc[i] * xt[j][i] * a4[i];
        sum += s[i];
        ssq += s[i] * s[i];
      }
      res[j] = s;
    }
    sum += __shfl_xor(sum, 1, 16);  ssq += __shfl_xor(ssq, 1, 16);
    sum += __shfl_xor(sum, 2, 16);  ssq += __shfl_xor(ssq, 2, 16);
    sum += __shfl_xor(sum, 4, 16);  ssq += __shfl_xor(ssq, 4, 16);
    sum += __shfl_xor(sum, 8, 16);  ssq += __shfl_xor(ssq, 8, 16);
    const float mu  = sum * inv_h;
    const float var = ssq * inv_h - mu * mu;
    const float rs  = rsqrtf(var + kEPS);

#pragma unroll
    for (int j = 0; j < 4; ++j) {
      const int lc = seg * 16 + 4 * j;
      const int cb = lc ^ r4;
      const float4 g4 = *(const float4*)(gamma + t * kH + lc);
      const float4 b4 = *(const float4*)(beta + t * kH + lc);
      float4 o;
#pragma unroll
      for (int i = 0; i < 4; ++i) o[i] = (res[j][i] - mu) * rs * g4[i] + b4[i];
      *(float4*)(sAcc + row_r * 256 + cb) = o;
    }
    __syncthreads();

    // coalesced non-temporal sweep: 8 waves x 4 rows
#pragma unroll
    for (int r8 = 0; r8 < 4; ++r8) {
      const int rr = wv * 4 + r8;
      const int rb = (rr & 7) << 2;
      const float4 v = *(const float4*)(sAcc + rr * 256 + ((4 * lane) ^ rb));
      ntstore4(out + (size_t)(slab * 64 + mt * 32 + rr) * (kT * kH) + t * kH + 4 * lane, v);
    }
  }
}

extern "C" void kernel_launch(void* const* d_in, const int* in_sizes, int n_in,
                              void* d_out, int out_size, void* d_ws, size_t ws_size,
                              hipStream_t stream) {
  const float* x      = (const float*)d_in[0];
  const float* w_in   = (const float*)d_in[1];
  const float* w_val  = (const float*)d_in[2];
  const float* alphas = (const float*)d_in[3];
  const float* scales = (const float*)d_in[4];
  const float* gamma  = (const float*)d_in[5];
  const float* beta   = (const float*)d_in[6];
  float* out = (float*)d_out;

  // ws: xp 4MB (64*32*2 chunks * 1KB) | wp 16MB (32*32*16 chunks * 1KB)
  u16* xp = (u16*)d_ws;
  u16* wp = xp + (size_t)64 * 32 * 2 * 512;

  pack_x_kernel<<<256, 256, 0, stream>>>(x, xp);
  pack_w_kernel<<<2048, 256, 0, stream>>>(w_in, w_val, wp);
  fused_kernel<<<kT * (kB / 64), 512, 0, stream>>>(xp, wp, alphas, scales,
                                                   gamma, beta, out);
}